// Round 9
// baseline (72.022 us; speedup 1.0000x reference)
//
#include <hip/hip_runtime.h>

#define FD 32          // feature dim
#define RPB 8          // rows per block  -> grid = 4096 blocks = 8 resident/CU
#define CPT 2          // cols per thread -> block covers 512 cols
#define BLK 256        // threads per block

// packed dual-fp32 add (B pre-negated in registers => computes a-b for 2 d's)
__device__ __forceinline__ float2 pk_add(float2 a, float2 b) {
    float2 r;
    asm("v_pk_add_f32 %0, %1, %2" : "=v"(r) : "v"(a), "v"(b));
    return r;
}
// acc = max(acc, |x|, |y|) in ONE VALU inst (abs = free VOP3 input modifier)
__device__ __forceinline__ float max3abs(float a, float x, float y) {
    float r;
    asm("v_max3_f32 %0, %1, abs(%2), abs(%3)" : "=v"(r) : "v"(a), "v"(x), "v"(y));
    return r;
}

// Plain 256: round 3 measured VGPR=44 for this exact body -> 8 waves/SIMD fit
// naturally. DO NOT add a min-waves bound (round 5: (256,8) capped VGPR=32 and
// spilled the B-set to scratch; round 4/7/8: bigger CPT loses B residency).
__global__ __launch_bounds__(256) void cheb_kernel(
    const float* __restrict__ A, const float* __restrict__ B,
    float* __restrict__ C, int M)
{
    const int tid = threadIdx.x;
    const int c0  = blockIdx.x * (BLK * CPT) + tid * CPT;  // this thread's 2 cols
    const int r0  = blockIdx.y * RPB;

    // ---- This thread's 2 B columns, negated, in 32 VGPRs.
    float2 nb0[FD / 2], nb1[FD / 2];
    {
        const float* brow = B + (size_t)c0 * FD;
#pragma unroll
        for (int q = 0; q < 8; ++q) {
            const float4 v = *reinterpret_cast<const float4*>(brow + q * 4);
            nb0[2 * q + 0] = make_float2(-v.x, -v.y);
            nb0[2 * q + 1] = make_float2(-v.z, -v.w);
            const float4 w = *reinterpret_cast<const float4*>(brow + FD + q * 4);
            nb1[2 * q + 0] = make_float2(-w.x, -w.y);
            nb1[2 * q + 1] = make_float2(-w.z, -w.w);
        }
    }

    // ---- Stream A rows (wave-uniform 16B loads, L1-broadcast; 32 waves/CU
    // of TLP hide the latency that bounded round 3 at 16 waves/CU).
#pragma unroll 2
    for (int r = 0; r < RPB; ++r) {
        const float* arow = A + (size_t)(r0 + r) * FD;
        float acc0 = 0.0f, acc1 = 0.0f;   // distances >= 0
#pragma unroll
        for (int q = 0; q < 8; ++q) {
            const float4 av = *reinterpret_cast<const float4*>(arow + q * 4);
            const float2 a01 = make_float2(av.x, av.y);
            const float2 a23 = make_float2(av.z, av.w);
            float2 d;
            d = pk_add(a01, nb0[2 * q + 0]); acc0 = max3abs(acc0, d.x, d.y);
            d = pk_add(a23, nb0[2 * q + 1]); acc0 = max3abs(acc0, d.x, d.y);
            d = pk_add(a01, nb1[2 * q + 0]); acc1 = max3abs(acc1, d.x, d.y);
            d = pk_add(a23, nb1[2 * q + 1]); acc1 = max3abs(acc1, d.x, d.y);
        }
        // coalesced: wave writes 512B contiguous
        *reinterpret_cast<float2*>(C + (size_t)(r0 + r) * M + c0) = make_float2(acc0, acc1);
    }
}

extern "C" void kernel_launch(void* const* d_in, const int* in_sizes, int n_in,
                              void* d_out, int out_size, void* d_ws, size_t ws_size,
                              hipStream_t stream) {
    const float* A = (const float*)d_in[0];
    const float* B = (const float*)d_in[1];
    float* C = (float*)d_out;
    const int N = in_sizes[0] / FD;   // 4096
    const int M = in_sizes[1] / FD;   // 4096
    dim3 grid(M / (BLK * CPT), N / RPB);   // 8 x 512 = 4096 blocks
    cheb_kernel<<<grid, BLK, 0, stream>>>(A, B, C, M);
}